// Round 3
// baseline (1770.115 us; speedup 1.0000x reference)
//
#include <hip/hip_runtime.h>
#include <hip/hip_bf16.h>
#include <hip/hip_cooperative_groups.h>

namespace cg = cooperative_groups;

#define B_ 512
#define T_ 49
#define I_ 96
#define H_ 1024

typedef __attribute__((ext_vector_type(4))) float f32x4;
typedef __attribute__((ext_vector_type(8))) short s16x8;

__device__ __forceinline__ unsigned short f2bf(float f) {
    unsigned int u = __float_as_uint(f);
    unsigned int r = (u + 0x7FFFu + ((u >> 16) & 1u)) >> 16;
    return (unsigned short)r;
}
__device__ __forceinline__ float sigmoidf_(float x) {
    return 1.0f / (1.0f + __expf(-x));
}
__device__ __forceinline__ float tanhf_(float x) {
    return 1.0f - 2.0f / (__expf(2.0f * x) + 1.0f);
}

// ---------------- quantize fp32 -> bf16 ----------------
__global__ void quantize_kernel(const float* __restrict__ Whh,
                                const float* __restrict__ Wih,
                                const float* __restrict__ x,
                                unsigned short* __restrict__ Whh_bf,
                                unsigned short* __restrict__ Wih_bf,
                                unsigned short* __restrict__ x_bf) {
    const long stride = (long)gridDim.x * blockDim.x;
    const long idx = (long)blockIdx.x * blockDim.x + threadIdx.x;

    const long nWhh4 = (long)3 * H_ * H_ / 4;
    const long nWih4 = (long)3 * H_ * I_ / 4;
    const long nX4   = (long)B_ * T_ * I_ / 4;

    for (long i = idx; i < nWhh4; i += stride) {
        float4 v = ((const float4*)Whh)[i];
        ushort4 o; o.x = f2bf(v.x); o.y = f2bf(v.y); o.z = f2bf(v.z); o.w = f2bf(v.w);
        ((ushort4*)Whh_bf)[i] = o;
    }
    for (long i = idx; i < nWih4; i += stride) {
        float4 v = ((const float4*)Wih)[i];
        ushort4 o; o.x = f2bf(v.x); o.y = f2bf(v.y); o.z = f2bf(v.z); o.w = f2bf(v.w);
        ((ushort4*)Wih_bf)[i] = o;
    }
    for (long i = idx; i < nX4; i += stride) {
        float4 v = ((const float4*)x)[i];
        ushort4 o; o.x = f2bf(v.x); o.y = f2bf(v.y); o.z = f2bf(v.z); o.w = f2bf(v.w);
        ((ushort4*)x_bf)[i] = o;
    }
}

// ---------------- persistent GRU kernel ----------------
// 256 blocks x 512 threads (8 waves), 1 block/CU (LDS-pinned), cooperative.
// Block tile: 128 b-rows x 16 j-cols x 3 gates. Wave w: rows [w*16, w*16+16).
// W_hh slice (3x16x1024 bf16) + W_ih slice live in LDS for the whole kernel.
// h: bf16 double-buffered in global (GEMM operand); each lane's own 4 h
// elements kept in fp32 registers for the z*h blend. One grid.sync per step.
// LDS pitch 1032 (=516 dw, mod32=4): rows rotate 4 banks -> <=2-way (free).
__global__ __launch_bounds__(512, 2)
void gru_persist(const unsigned short* __restrict__ Whh_bf,
                 const unsigned short* __restrict__ Wih_bf,
                 const unsigned short* __restrict__ x_bf,
                 const float* __restrict__ b_ih,
                 const float* __restrict__ b_hh,
                 unsigned short* __restrict__ hbf0,
                 unsigned short* __restrict__ hbf1,
                 float* __restrict__ out)
{
    const int tid = threadIdx.x;
    const int w   = tid >> 6;
    const int l   = tid & 63;
    const int l15 = l & 15;
    const int l4  = l >> 4;

    // block mapping: xcd = bid&7; each XCD: 1 b-slice x 32 j-tiles
    const int bid  = blockIdx.x;
    const int xcd  = bid & 7;
    const int idx  = bid >> 3;              // 0..31
    const int blkb = xcd >> 1;              // 0..3  (XCD pair shares b-slice)
    const int blkj = (xcd & 1) * 32 + idx;  // 0..63
    const int b0   = blkb * 128;
    const int j0   = blkj * 16;
    const int wb   = b0 + w * 16;

    __shared__ __align__(16) unsigned short Wl[3][16][1032]; // 99,072 B
    __shared__ __align__(16) unsigned short Wi[3][16][104];  //  9,984 B

    // ---- one-time: load W_hh / W_ih slices into LDS ----
    for (int c = tid; c < 48 * 128; c += 512) {       // 16B chunks of W_hh slice
        const int row = c >> 7, ch = c & 127;
        const int g = row >> 4, jj = row & 15;
        *(s16x8*)&Wl[g][jj][ch * 8] =
            *(const s16x8*)(Whh_bf + ((long)g * H_ + j0 + jj) * H_ + ch * 8);
    }
    for (int c = tid; c < 48 * 12; c += 512) {        // 16B chunks of W_ih slice
        const int row = c / 12, ch = c - row * 12;
        const int g = row >> 4, jj = row & 15;
        *(s16x8*)&Wi[g][jj][ch * 8] =
            *(const s16x8*)(Wih_bf + ((long)g * H_ + j0 + jj) * I_ + ch * 8);
    }

    // ---- per-lane constants ----
    const int jg = j0 + l15;
    const float bR   = b_ih[jg] + b_hh[jg];
    const float bZ   = b_ih[H_ + jg] + b_hh[H_ + jg];
    const float bihN = b_ih[2 * H_ + jg];
    const float bhhN = b_hh[2 * H_ + jg];

    float hreg[4] = {0.f, 0.f, 0.f, 0.f};

    __syncthreads();

    cg::grid_group grid = cg::this_grid();

    for (int t = 0; t < T_; ++t) {
        if (t > 0) grid.sync();   // h[t-1] fully written device-wide

        f32x4 aR  = (f32x4){0.f, 0.f, 0.f, 0.f};
        f32x4 aZ  = (f32x4){0.f, 0.f, 0.f, 0.f};
        f32x4 aNi = (f32x4){0.f, 0.f, 0.f, 0.f};
        f32x4 aNh = (f32x4){0.f, 0.f, 0.f, 0.f};

        // ---- input GEMM: gi = x_t @ W_ih^T (K=96, direct from global) ----
        {
            const s16x8* Ax = (const s16x8*)(x_bf + ((long)(wb + l15) * T_ + t) * I_ + 8 * l4);
#pragma unroll
            for (int ks = 0; ks < 3; ++ks) {
                s16x8 a  = Ax[ks * 4];
                s16x8 br = *(const s16x8*)&Wi[0][l15][ks * 32 + l4 * 8];
                s16x8 bz = *(const s16x8*)&Wi[1][l15][ks * 32 + l4 * 8];
                s16x8 bn = *(const s16x8*)&Wi[2][l15][ks * 32 + l4 * 8];
                aR  = __builtin_amdgcn_mfma_f32_16x16x32_bf16(a, br, aR, 0, 0, 0);
                aZ  = __builtin_amdgcn_mfma_f32_16x16x32_bf16(a, bz, aZ, 0, 0, 0);
                aNi = __builtin_amdgcn_mfma_f32_16x16x32_bf16(a, bn, aNi, 0, 0, 0);
            }
        }

        // ---- recurrent GEMM: gh = h @ W_hh^T (K=1024, W from LDS, A from global) ----
        if (t > 0) {
            const unsigned short* hin = (t & 1) ? hbf0 : hbf1;
            const s16x8* Ah = (const s16x8*)(hin + (long)(wb + l15) * H_ + 8 * l4);
            // 4-kstep register prefetch (kstep stride = 4 s16x8 units)
            s16x8 a0 = Ah[0], a1 = Ah[4], a2 = Ah[8], a3 = Ah[12];
#pragma unroll
            for (int kb = 0; kb < 8; ++kb) {
                s16x8 n0, n1, n2, n3;
                if (kb < 7) {
                    const s16x8* An = Ah + (kb + 1) * 16;
                    n0 = An[0]; n1 = An[4]; n2 = An[8]; n3 = An[12];
                }
#pragma unroll
                for (int q = 0; q < 4; ++q) {
                    const int ks = kb * 4 + q;
                    s16x8 a  = (q == 0) ? a0 : (q == 1) ? a1 : (q == 2) ? a2 : a3;
                    s16x8 br = *(const s16x8*)&Wl[0][l15][ks * 32 + l4 * 8];
                    s16x8 bz = *(const s16x8*)&Wl[1][l15][ks * 32 + l4 * 8];
                    s16x8 bn = *(const s16x8*)&Wl[2][l15][ks * 32 + l4 * 8];
                    aR  = __builtin_amdgcn_mfma_f32_16x16x32_bf16(a, br, aR, 0, 0, 0);
                    aZ  = __builtin_amdgcn_mfma_f32_16x16x32_bf16(a, bz, aZ, 0, 0, 0);
                    aNh = __builtin_amdgcn_mfma_f32_16x16x32_bf16(a, bn, aNh, 0, 0, 0);
                }
                a0 = n0; a1 = n1; a2 = n2; a3 = n3;
            }
        }

        // ---- epilogue: gates + blend, h kept in registers ----
        unsigned short* hout = (t & 1) ? hbf1 : hbf0;
#pragma unroll
        for (int r = 0; r < 4; ++r) {
            const float rg = sigmoidf_(aR[r] + bR);
            const float zg = sigmoidf_(aZ[r] + bZ);
            const float ng = tanhf_(aNi[r] + bihN + rg * (aNh[r] + bhhN));
            hreg[r] = (1.0f - zg) * ng + zg * hreg[r];
            const long off = (long)(wb + l4 * 4 + r) * H_ + jg;
            if (t < T_ - 1) hout[off] = f2bf(hreg[r]);
            else            out[off]  = hreg[r];
        }
    }
}

extern "C" void kernel_launch(void* const* d_in, const int* in_sizes, int n_in,
                              void* d_out, int out_size, void* d_ws, size_t ws_size,
                              hipStream_t stream) {
    const float* enc_in = (const float*)d_in[0];
    const float* W_ih   = (const float*)d_in[1];
    const float* W_hh   = (const float*)d_in[2];
    const float* b_ih   = (const float*)d_in[3];
    const float* b_hh   = (const float*)d_in[4];
    float* out = (float*)d_out;

    char* ws = (char*)d_ws;
    unsigned short* Whh_bf = (unsigned short*)(ws);             // 6,291,456 B
    unsigned short* Wih_bf = (unsigned short*)(ws + 6291456);   //   589,824 B
    unsigned short* x_bf   = (unsigned short*)(ws + 6881280);   // 4,816,896 B
    unsigned short* hbf0   = (unsigned short*)(ws + 11698176);  // 1,048,576 B
    unsigned short* hbf1   = (unsigned short*)(ws + 12746752);  // 1,048,576 B

    quantize_kernel<<<dim3(1024), dim3(256), 0, stream>>>(W_hh, W_ih, enc_in,
                                                          Whh_bf, Wih_bf, x_bf);

    void* args[] = {(void*)&Whh_bf, (void*)&Wih_bf, (void*)&x_bf,
                    (void*)&b_ih, (void*)&b_hh,
                    (void*)&hbf0, (void*)&hbf1, (void*)&out};
    hipLaunchCooperativeKernel((const void*)gru_persist,
                               dim3(256), dim3(512), args, 0, stream);
}

// Round 4
// 664.814 us; speedup vs baseline: 2.6626x; 2.6626x over previous
//
#include <hip/hip_runtime.h>
#include <hip/hip_bf16.h>

#define B_ 512
#define T_ 49
#define I_ 96
#define H_ 1024

typedef __attribute__((ext_vector_type(4))) float f32x4;
typedef __attribute__((ext_vector_type(8))) short s16x8;

__device__ __forceinline__ unsigned short f2bf(float f) {
    unsigned int u = __float_as_uint(f);
    unsigned int r = (u + 0x7FFFu + ((u >> 16) & 1u)) >> 16;
    return (unsigned short)r;
}
__device__ __forceinline__ float sigmoidf_(float x) {
    return 1.0f / (1.0f + __expf(-x));
}
__device__ __forceinline__ float tanhf_(float x) {
    return 1.0f - 2.0f / (__expf(2.0f * x) + 1.0f);
}

// ------------- quantize fp32 -> bf16; x transposed to [t][b][i] -------------
__global__ void quantize_kernel(const float* __restrict__ Whh,
                                const float* __restrict__ Wih,
                                const float* __restrict__ x,
                                unsigned short* __restrict__ Whh_bf,
                                unsigned short* __restrict__ Wih_bf,
                                unsigned short* __restrict__ xT_bf) {
    const long stride = (long)gridDim.x * blockDim.x;
    const long idx = (long)blockIdx.x * blockDim.x + threadIdx.x;

    const long nWhh4 = (long)3 * H_ * H_ / 4;
    const long nWih4 = (long)3 * H_ * I_ / 4;
    const long nX4   = (long)B_ * T_ * I_ / 4;

    for (long i = idx; i < nWhh4; i += stride) {
        float4 v = ((const float4*)Whh)[i];
        ushort4 o; o.x = f2bf(v.x); o.y = f2bf(v.y); o.z = f2bf(v.z); o.w = f2bf(v.w);
        ((ushort4*)Whh_bf)[i] = o;
    }
    for (long i = idx; i < nWih4; i += stride) {
        float4 v = ((const float4*)Wih)[i];
        ushort4 o; o.x = f2bf(v.x); o.y = f2bf(v.y); o.z = f2bf(v.z); o.w = f2bf(v.w);
        ((ushort4*)Wih_bf)[i] = o;
    }
    for (long i = idx; i < nX4; i += stride) {
        float4 v = ((const float4*)x)[i];
        ushort4 o; o.x = f2bf(v.x); o.y = f2bf(v.y); o.z = f2bf(v.z); o.w = f2bf(v.w);
        const long e = i * 4;                 // flat elem idx in [b][t][i]
        const int b  = (int)(e / (T_ * I_));
        const int rm = (int)(e - (long)b * (T_ * I_));
        const int tt = rm / I_;
        const int ii = rm - tt * I_;
        ((ushort4*)xT_bf)[(((long)tt * B_ + b) * I_ + ii) >> 2] = o;
    }
}

// ---------------- one GRU step (v2) ----------------
// 256 blocks x 512 thr (8 waves, 2/SIMD, 1 block/CU). Tile 128b x 16j x 3g.
// Wave w: b-rows [w*16, w*16+16), all 16 j. W_hh slice staged LDS-only in
// 4 double-buffered kc=256 chunks (pitch 264: 132dw = 4 mod 32, ~conflict-
// free). A-operand (h rows, wave-exclusive) global->reg, one chunk ahead.
__global__ __launch_bounds__(512)
void gru_step2(const unsigned short* __restrict__ Whh_bf,
               const unsigned short* __restrict__ Wih_bf,
               const unsigned short* __restrict__ xT_bf,
               const float* __restrict__ b_ih,
               const float* __restrict__ b_hh,
               const float* __restrict__ h_in,            // fp32 prev h
               const unsigned short* __restrict__ hbf_in, // bf16 prev h
               float* __restrict__ h_out,
               unsigned short* __restrict__ hbf_out,
               int t, int first)
{
    const int tid = threadIdx.x;
    const int w   = tid >> 6;
    const int l   = tid & 63;
    const int l15 = l & 15;
    const int l4  = l >> 4;

    const int bid  = blockIdx.x;
    const int xcd  = bid & 7;
    const int r_   = bid >> 3;            // 0..31
    const int blkb = r_ & 3;              // 4 b-tiles of 128
    const int blkj = xcd * 8 + (r_ >> 2); // 64 j-tiles of 16, XCD-grouped
    const int b0   = blkb * 128;
    const int j0   = blkj * 16;
    const int wb   = b0 + w * 16;

    __shared__ __align__(16) unsigned short Wl[2][3][16][264];  // 50,688 B

    f32x4 aR  = (f32x4){0.f, 0.f, 0.f, 0.f};
    f32x4 aZ  = (f32x4){0.f, 0.f, 0.f, 0.f};
    f32x4 aNi = (f32x4){0.f, 0.f, 0.f, 0.f};
    f32x4 aNh = (f32x4){0.f, 0.f, 0.f, 0.f};

    // W-stage mapping: thread -> gate p rows jj=tid>>5, 16B chunk ch=tid&31
    const int jj = tid >> 5;
    const int ch = tid & 31;
    s16x8 sw0, sw1, sw2;

#define WSTAGE_LOAD(c) {                                                       \
    const long ko = (long)(c) * 256 + ch * 8;                                  \
    sw0 = *(const s16x8*)(Whh_bf + ((long)(           j0 + jj)) * H_ + ko);    \
    sw1 = *(const s16x8*)(Whh_bf + ((long)(H_     +   j0 + jj)) * H_ + ko);    \
    sw2 = *(const s16x8*)(Whh_bf + ((long)(2 * H_ +   j0 + jj)) * H_ + ko); }

#define WSTAGE_WRITE(buf) {                                                    \
    *(s16x8*)&Wl[buf][0][jj][ch * 8] = sw0;                                    \
    *(s16x8*)&Wl[buf][1][jj][ch * 8] = sw1;                                    \
    *(s16x8*)&Wl[buf][2][jj][ch * 8] = sw2; }

    const unsigned short* Abase = hbf_in + (long)(wb + l15) * H_ + l4 * 8;
    s16x8 Acur[8];
    float hp[4] = {0.f, 0.f, 0.f, 0.f};
    const int jg = j0 + l15;

    if (!first) {
        WSTAGE_LOAD(0);
#pragma unroll
        for (int q = 0; q < 8; ++q)
            Acur[q] = *(const s16x8*)(Abase + q * 32);
        // prefetch blend inputs early
#pragma unroll
        for (int r = 0; r < 4; ++r)
            hp[r] = h_in[(long)(wb + l4 * 4 + r) * H_ + jg];
    }

    // ---- input GEMM: gi = x_t @ W_ih^T (K=96, direct from global) ----
    {
        const unsigned short* Ax = xT_bf + ((long)t * B_ + (wb + l15)) * I_ + l4 * 8;
        const unsigned short* Vr = Wih_bf + (long)(j0 + l15) * I_ + l4 * 8;
        const unsigned short* Vz = Wih_bf + (long)(H_ + j0 + l15) * I_ + l4 * 8;
        const unsigned short* Vn = Wih_bf + (long)(2 * H_ + j0 + l15) * I_ + l4 * 8;
#pragma unroll
        for (int ks = 0; ks < 3; ++ks) {
            s16x8 a  = *(const s16x8*)(Ax + ks * 32);
            s16x8 br = *(const s16x8*)(Vr + ks * 32);
            s16x8 bz = *(const s16x8*)(Vz + ks * 32);
            s16x8 bn = *(const s16x8*)(Vn + ks * 32);
            aR  = __builtin_amdgcn_mfma_f32_16x16x32_bf16(a, br, aR, 0, 0, 0);
            aZ  = __builtin_amdgcn_mfma_f32_16x16x32_bf16(a, bz, aZ, 0, 0, 0);
            aNi = __builtin_amdgcn_mfma_f32_16x16x32_bf16(a, bn, aNi, 0, 0, 0);
        }
    }

    // ---- recurrent GEMM: gh = h @ W_hh^T (K=1024, 4 chunks of 256) ----
    if (!first) {
        WSTAGE_WRITE(0);
        __syncthreads();
#pragma unroll
        for (int c = 0; c < 4; ++c) {
            s16x8 An[8];
            if (c < 3) {
                WSTAGE_LOAD(c + 1);
#pragma unroll
                for (int q = 0; q < 8; ++q)
                    An[q] = *(const s16x8*)(Abase + ((c + 1) * 8 + q) * 32);
            }
#pragma unroll
            for (int q = 0; q < 8; ++q) {
                s16x8 br = *(const s16x8*)&Wl[c & 1][0][l15][q * 32 + l4 * 8];
                s16x8 bz = *(const s16x8*)&Wl[c & 1][1][l15][q * 32 + l4 * 8];
                s16x8 bn = *(const s16x8*)&Wl[c & 1][2][l15][q * 32 + l4 * 8];
                aR  = __builtin_amdgcn_mfma_f32_16x16x32_bf16(Acur[q], br, aR, 0, 0, 0);
                aZ  = __builtin_amdgcn_mfma_f32_16x16x32_bf16(Acur[q], bz, aZ, 0, 0, 0);
                aNh = __builtin_amdgcn_mfma_f32_16x16x32_bf16(Acur[q], bn, aNh, 0, 0, 0);
            }
            if (c < 3) {
                WSTAGE_WRITE((c & 1) ^ 1);
                __syncthreads();
#pragma unroll
                for (int q = 0; q < 8; ++q) Acur[q] = An[q];
            }
        }
    }
#undef WSTAGE_LOAD
#undef WSTAGE_WRITE

    // ---- epilogue: gates + blend (fp32) ----
    const float bR   = b_ih[jg] + b_hh[jg];
    const float bZ   = b_ih[H_ + jg] + b_hh[H_ + jg];
    const float bihN = b_ih[2 * H_ + jg];
    const float bhhN = b_hh[2 * H_ + jg];

#pragma unroll
    for (int r = 0; r < 4; ++r) {
        const int row = wb + l4 * 4 + r;
        const long off = (long)row * H_ + jg;
        const float rg = sigmoidf_(aR[r] + bR);
        const float zg = sigmoidf_(aZ[r] + bZ);
        const float ng = tanhf_(aNi[r] + bihN + rg * (aNh[r] + bhhN));
        const float hn = (1.0f - zg) * ng + zg * hp[r];
        h_out[off] = hn;
        hbf_out[off] = f2bf(hn);
    }
}

extern "C" void kernel_launch(void* const* d_in, const int* in_sizes, int n_in,
                              void* d_out, int out_size, void* d_ws, size_t ws_size,
                              hipStream_t stream) {
    const float* enc_in = (const float*)d_in[0];
    const float* W_ih   = (const float*)d_in[1];
    const float* W_hh   = (const float*)d_in[2];
    const float* b_ih   = (const float*)d_in[3];
    const float* b_hh   = (const float*)d_in[4];
    float* out = (float*)d_out;

    char* ws = (char*)d_ws;
    unsigned short* Whh_bf = (unsigned short*)(ws);             // 6,291,456 B
    unsigned short* Wih_bf = (unsigned short*)(ws + 6291456);   //   589,824 B
    unsigned short* xT_bf  = (unsigned short*)(ws + 6881280);   // 4,816,896 B
    float* hA              = (float*)(ws + 11698176);           // 2,097,152 B
    float* hB              = (float*)(ws + 13795328);           // 2,097,152 B
    unsigned short* hbfA   = (unsigned short*)(ws + 15892480);  // 1,048,576 B
    unsigned short* hbfB   = (unsigned short*)(ws + 16941056);  // 1,048,576 B

    quantize_kernel<<<dim3(1024), dim3(256), 0, stream>>>(W_hh, W_ih, enc_in,
                                                          Whh_bf, Wih_bf, xT_bf);

    for (int t = 0; t < T_; ++t) {
        const int first = (t == 0) ? 1 : 0;
        float* hi; unsigned short* hbi; float* ho; unsigned short* hbo;
        if (t & 1) { hi = hA; hbi = hbfA; ho = hB; hbo = hbfB; }
        else       { hi = hB; hbi = hbfB; ho = hA; hbo = hbfA; }
        if (t == T_ - 1) ho = out;  // last step writes d_out directly
        gru_step2<<<dim3(256), dim3(512), 0, stream>>>(Whh_bf, Wih_bf, xT_bf,
                                                       b_ih, b_hh, hi, hbi, ho, hbo,
                                                       t, first);
    }
}